// Round 9
// baseline (1587.611 us; speedup 1.0000x reference)
//
#include <hip/hip_runtime.h>
#include <hip/hip_bf16.h>
#include <math.h>

// ---------------------------------------------------------------------------
// LIF layer, round 9: FAST bf16x3 MFMA GEMM + banded f32 scan + EXACT repair.
//
// Reference semantics (R8-verified, PASSING): cur = x @ W^T + b computed by
// OpenBLAS sgemm order = K-panels of Q=320, sequential FMA inside a panel,
// C = ((P0+P1)+P2)+...; then f32 scan: mem = mem*decay + cur (mul, add),
// spk = (mem-1 > 0), mem -= 1 if spk.
//
// Strategy: matrix-core fast path (error ~1e-5) + bit-exact repair of the
// ~6% of chains that ever come within BAND=2e-3 of the threshold. Chains
// outside the band provably decide identically to the exact computation.
//   k1 zero   : counter = 0
//   k2 split  : A,W f32 -> bf16 hi/lo pairs in d_ws (Dekker split, exact)
//   k3 gemm   : 128x128x32 tiles, mfma_16x16x32_bf16 x3 (hh + hl + lh),
//               cur_fast -> d_out
//   k4 scan   : exact-f32 scan ops on cur_fast, in-place spikes 1.0/0.0,
//               flag tight chains -> worklist (atomicAdd)
//   k5 repair : per flagged chain, recompute 64 exact dot products
//               (Q=320 panel order) + exact scan, overwrite column.
// Fallback: if ws_size < needed, run the R8 fused kernel (known-passing).
// ---------------------------------------------------------------------------

typedef unsigned short u16;
typedef __attribute__((ext_vector_type(8))) short bf16x8;   // 8 bf16 = 4 VGPR
typedef __attribute__((ext_vector_type(4))) float f32x4;

constexpr int T_STEPS = 64;
constexpr int BATCH   = 128;
constexpr int K_DIM   = 2048;
constexpr int N_DIM   = 2048;
constexpr int M_DIM   = T_STEPS * BATCH;      // 8192
constexpr int NCHAIN  = BATCH * N_DIM;        // 262144

constexpr float DECAY_F32 = (float)0.6065306597126334;  // f32(exp(-0.5))
constexpr float BAND      = 2e-3f;

// ---------------------------------------------------------------------------
// k1: zero the worklist counter
// ---------------------------------------------------------------------------
__global__ void zero_u32(unsigned int* p) { *p = 0u; }

// ---------------------------------------------------------------------------
// k2: Dekker split of A (M*K) and W (N*K) f32 -> bf16 hi/lo. 4 elems/thread.
// ---------------------------------------------------------------------------
__global__ __launch_bounds__(256)
void split_bf16(const float* __restrict__ X, const float* __restrict__ W,
                u16* __restrict__ Ah, u16* __restrict__ Al,
                u16* __restrict__ Wh, u16* __restrict__ Wl) {
    constexpr int NA4 = (M_DIM * K_DIM) / 4;   // 4194304
    constexpr int NW4 = (N_DIM * K_DIM) / 4;   // 1048576
    const int i = blockIdx.x * 256 + threadIdx.x;
    const float* src; u16* dh; u16* dl; int base;
    if (i < NA4)            { src = X; dh = Ah; dl = Al; base = i; }
    else if (i < NA4 + NW4) { src = W; dh = Wh; dl = Wl; base = i - NA4; }
    else return;

    const float4 v = *(const float4*)(src + (size_t)base * 4);
    const float f[4] = {v.x, v.y, v.z, v.w};
    unsigned int hp[2], lp[2];
#pragma unroll
    for (int q = 0; q < 4; q += 2) {
        u16 hh[2], ll[2];
#pragma unroll
        for (int e = 0; e < 2; e++) {
            __hip_bfloat16 hb = __float2bfloat16(f[q + e]);
            const float hf = __bfloat162float(hb);
            __hip_bfloat16 lb = __float2bfloat16(f[q + e] - hf);  // residual exact in f32
            hh[e] = *(u16*)&hb;
            ll[e] = *(u16*)&lb;
        }
        hp[q >> 1] = (unsigned int)hh[0] | ((unsigned int)hh[1] << 16);
        lp[q >> 1] = (unsigned int)ll[0] | ((unsigned int)ll[1] << 16);
    }
    *(uint2*)(dh + (size_t)base * 4) = make_uint2(hp[0], hp[1]);
    *(uint2*)(dl + (size_t)base * 4) = make_uint2(lp[0], lp[1]);
}

// ---------------------------------------------------------------------------
// k3: bf16x3 MFMA GEMM. 128x128 tile, BK=32, 256 threads (4 waves, 2x2 grid,
// each wave 64x64 = 4x4 tiles of 16x16). LDS holds fragment-ordered tiles:
// chunk c (0..511 per array): tile=c>>6, lane=c&63 -> element
// [tilebase + tile*16 + (lane&15)][k0 + (lane>>4)*8 .. +8]; frag ds_read is
// lane*16B contiguous -> conflict-free.
// ---------------------------------------------------------------------------
__global__ __launch_bounds__(256, 2)
void gemm_bf16x3(const u16* __restrict__ Ah, const u16* __restrict__ Al,
                 const u16* __restrict__ Bh, const u16* __restrict__ Bl,
                 const float* __restrict__ bias, float* __restrict__ C) {
    __shared__ __align__(16) u16 sAh[4096], sAl[4096], sBh[4096], sBl[4096];

    const int tid  = threadIdx.x;
    const int m0   = blockIdx.y * 128;
    const int n0   = blockIdx.x * 128;
    const int lane = tid & 63;
    const int wave = tid >> 6;
    const int wm   = wave >> 1;          // 0..1
    const int wn   = wave & 1;           // 0..1

    // staging chunk offsets (2 chunks per thread per array)
    const int c0 = tid, c1 = tid + 256;
#define OFFA(c) ((size_t)(m0 + ((c) >> 6) * 16 + ((c) & 15)) * K_DIM + (((c) >> 4) & 3) * 8)
#define OFFB(c) ((size_t)(n0 + ((c) >> 6) * 16 + ((c) & 15)) * K_DIM + (((c) >> 4) & 3) * 8)
    const size_t a0 = OFFA(c0), a1 = OFFA(c1);
    const size_t b0 = OFFB(c0), b1 = OFFB(c1);
#undef OFFA
#undef OFFB

    f32x4 acc[4][4];
#pragma unroll
    for (int i = 0; i < 4; i++)
#pragma unroll
        for (int j = 0; j < 4; j++) acc[i][j] = (f32x4){0.f, 0.f, 0.f, 0.f};

    for (int kc = 0; kc < K_DIM / 32; kc++) {
        const int k0 = kc * 32;
        // global loads (16B each) into regs
        const uint4 vah0 = *(const uint4*)(Ah + a0 + k0);
        const uint4 vah1 = *(const uint4*)(Ah + a1 + k0);
        const uint4 val0 = *(const uint4*)(Al + a0 + k0);
        const uint4 val1 = *(const uint4*)(Al + a1 + k0);
        const uint4 vbh0 = *(const uint4*)(Bh + b0 + k0);
        const uint4 vbh1 = *(const uint4*)(Bh + b1 + k0);
        const uint4 vbl0 = *(const uint4*)(Bl + b0 + k0);
        const uint4 vbl1 = *(const uint4*)(Bl + b1 + k0);
        __syncthreads();   // previous iteration's frag reads done
        *(uint4*)&sAh[c0 * 8] = vah0;  *(uint4*)&sAh[c1 * 8] = vah1;
        *(uint4*)&sAl[c0 * 8] = val0;  *(uint4*)&sAl[c1 * 8] = val1;
        *(uint4*)&sBh[c0 * 8] = vbh0;  *(uint4*)&sBh[c1 * 8] = vbh1;
        *(uint4*)&sBl[c0 * 8] = vbl0;  *(uint4*)&sBl[c1 * 8] = vbl1;
        __syncthreads();

        bf16x8 fah[4], fal[4], fbh[4], fbl[4];
#pragma unroll
        for (int ti = 0; ti < 4; ti++) {
            const int ta = wm * 4 + ti;
            fah[ti] = *(const bf16x8*)&sAh[(ta * 64 + lane) * 8];
            fal[ti] = *(const bf16x8*)&sAl[(ta * 64 + lane) * 8];
        }
#pragma unroll
        for (int tj = 0; tj < 4; tj++) {
            const int tb = wn * 4 + tj;
            fbh[tj] = *(const bf16x8*)&sBh[(tb * 64 + lane) * 8];
            fbl[tj] = *(const bf16x8*)&sBl[(tb * 64 + lane) * 8];
        }
#pragma unroll
        for (int ti = 0; ti < 4; ti++)
#pragma unroll
            for (int tj = 0; tj < 4; tj++) {
                acc[ti][tj] = __builtin_amdgcn_mfma_f32_16x16x32_bf16(
                    fah[ti], fbh[tj], acc[ti][tj], 0, 0, 0);
                acc[ti][tj] = __builtin_amdgcn_mfma_f32_16x16x32_bf16(
                    fah[ti], fbl[tj], acc[ti][tj], 0, 0, 0);
                acc[ti][tj] = __builtin_amdgcn_mfma_f32_16x16x32_bf16(
                    fal[ti], fbh[tj], acc[ti][tj], 0, 0, 0);
            }
    }

    // epilogue: C/D layout col = lane&15, row = (lane>>4)*4 + r
#pragma unroll
    for (int tj = 0; tj < 4; tj++) {
        const int n  = n0 + wn * 64 + tj * 16 + (lane & 15);
        const float bv = bias[n];
#pragma unroll
        for (int ti = 0; ti < 4; ti++) {
            const int mbase = m0 + wm * 64 + ti * 16 + (lane >> 4) * 4;
#pragma unroll
            for (int r = 0; r < 4; r++)
                C[(size_t)(mbase + r) * N_DIM + n] = acc[ti][tj][r] + bv;
        }
    }
}

// ---------------------------------------------------------------------------
// k4: banded scan. Exact f32 ops on cur_fast (in d_out), spikes in-place.
// Chains with any |mem-1| < BAND -> worklist.
// ---------------------------------------------------------------------------
__global__ __launch_bounds__(256)
void lif_scan_band(float* __restrict__ buf, unsigned int* __restrict__ counter,
                   unsigned int* __restrict__ worklist) {
    const int idx = blockIdx.x * 256 + threadIdx.x;   // chain id = b*2048+o
    float mem = 0.0f;
    bool flag = false;
#pragma unroll
    for (int t = 0; t < T_STEPS; t++) {
        const size_t off = (size_t)t * NCHAIN + idx;
        mem = __fadd_rn(__fmul_rn(mem, DECAY_F32), buf[off]);
        const float d = __fsub_rn(mem, 1.0f);
        const bool spk = d > 0.0f;
        if (fabsf(d) < BAND) flag = true;
        buf[off] = spk ? 1.0f : 0.0f;
        if (spk) mem = __fsub_rn(mem, 1.0f);
    }
    if (flag) {
        const unsigned int p = atomicAdd(counter, 1u);
        worklist[p] = (unsigned int)idx;   // worklist sized NCHAIN: no overflow
    }
}

// ---------------------------------------------------------------------------
// k5: exact repair. One block (64 threads) per flagged chain; thread t does
// the bit-exact Q=320-panel dot product for timestep t; thread 0 scans.
// ---------------------------------------------------------------------------
__global__ __launch_bounds__(64)
void lif_repair(const float* __restrict__ X, const float* __restrict__ W,
                const float* __restrict__ bias,
                const unsigned int* __restrict__ counter,
                const unsigned int* __restrict__ worklist,
                float* __restrict__ out) {
    __shared__ float scur[T_STEPS];
    __shared__ float sspk[T_STEPS];
    const unsigned int n = *counter;
    const int t = threadIdx.x;
    for (unsigned int wi = blockIdx.x; wi < n; wi += gridDim.x) {
        const unsigned int idx = worklist[wi];
        const int b = idx >> 11, o = idx & 2047;
        const float* xr = X + (size_t)(t * BATCH + b) * K_DIM;
        const float* wr = W + (size_t)o * K_DIM;
        float Csum = 0.0f;
        int k = 0;
        for (int p = 0; p < 7; p++) {                 // 6x320 + 128
            const int kend = k + ((p < 6) ? 320 : 128);
            float P = 0.0f;
            for (; k < kend; k++) P = fmaf(xr[k], wr[k], P);
            Csum = __fadd_rn(Csum, P);
        }
        scur[t] = __fadd_rn(Csum, bias[o]);
        __syncthreads();
        if (t == 0) {
            float mem = 0.0f;
            for (int tt = 0; tt < T_STEPS; tt++) {
                mem = __fadd_rn(__fmul_rn(mem, DECAY_F32), scur[tt]);
                const float d = __fsub_rn(mem, 1.0f);
                const bool spk = d > 0.0f;
                sspk[tt] = spk ? 1.0f : 0.0f;
                if (spk) mem = __fsub_rn(mem, 1.0f);
            }
        }
        __syncthreads();
        out[(size_t)t * NCHAIN + idx] = sspk[t];
        __syncthreads();
    }
}

// ---------------------------------------------------------------------------
// FALLBACK (R8, known-passing, ws-free): fused OpenBLAS-Q320 + scan.
// ---------------------------------------------------------------------------
__global__ __launch_bounds__(256)
void lif_openblas_q320(const float* __restrict__ X, const float* __restrict__ W,
                       const float* __restrict__ bias, float* __restrict__ out) {
    __shared__ float As[16][T_STEPS + 4];
    __shared__ float Ws[16][64 + 4];
    __shared__ float curbuf[T_STEPS][64 + 1];
    const int tid = threadIdx.x;
    const int o0 = blockIdx.x * 64, b0 = blockIdx.y;
    const int tm = (tid & 15) * 4, tn = (tid >> 4) * 4;
    float Csum[4][4], Pacc[4][4];
#pragma unroll
    for (int i = 0; i < 4; i++)
#pragma unroll
        for (int j = 0; j < 4; j++) { Csum[i][j] = 0.f; Pacc[i][j] = 0.f; }
    for (int c = 0; c < K_DIM / 16; c++) {
        if (c > 0 && (c % 20) == 0) {
#pragma unroll
            for (int i = 0; i < 4; i++)
#pragma unroll
                for (int j = 0; j < 4; j++) {
                    Csum[i][j] = __fadd_rn(Csum[i][j], Pacc[i][j]);
                    Pacc[i][j] = 0.f;
                }
        }
        const int k0 = c * 16;
        {
            const int t = tid >> 2, kq = (tid & 3) * 4;
            const float4 av = *(const float4*)&X[(size_t)(t * BATCH + b0) * K_DIM + k0 + kq];
            As[kq + 0][t] = av.x; As[kq + 1][t] = av.y;
            As[kq + 2][t] = av.z; As[kq + 3][t] = av.w;
            const float4 wv = *(const float4*)&W[(size_t)(o0 + t) * K_DIM + k0 + kq];
            Ws[kq + 0][t] = wv.x; Ws[kq + 1][t] = wv.y;
            Ws[kq + 2][t] = wv.z; Ws[kq + 3][t] = wv.w;
        }
        __syncthreads();
#pragma unroll
        for (int k = 0; k < 16; k++) {
            float a[4], w[4];
#pragma unroll
            for (int i = 0; i < 4; i++) a[i] = As[k][tm + i];
#pragma unroll
            for (int j = 0; j < 4; j++) w[j] = Ws[k][tn + j];
#pragma unroll
            for (int i = 0; i < 4; i++)
#pragma unroll
                for (int j = 0; j < 4; j++) Pacc[i][j] = fmaf(a[i], w[j], Pacc[i][j]);
        }
        __syncthreads();
    }
#pragma unroll
    for (int i = 0; i < 4; i++)
#pragma unroll
        for (int j = 0; j < 4; j++)
            curbuf[tm + i][tn + j] =
                __fadd_rn(__fadd_rn(Csum[i][j], Pacc[i][j]), bias[o0 + tn + j]);
    __syncthreads();
    if (tid < 64) {
        float mem = 0.0f;
#pragma unroll
        for (int t = 0; t < T_STEPS; t++) {
            mem = __fadd_rn(__fmul_rn(mem, DECAY_F32), curbuf[t][tid]);
            const float d = __fsub_rn(mem, 1.0f);
            const bool spk = d > 0.0f;
            out[(size_t)t * NCHAIN + (size_t)b0 * N_DIM + o0 + tid] = spk ? 1.0f : 0.0f;
            if (spk) mem = __fsub_rn(mem, 1.0f);
        }
    }
}

extern "C" void kernel_launch(void* const* d_in, const int* in_sizes, int n_in,
                              void* d_out, int out_size, void* d_ws, size_t ws_size,
                              hipStream_t stream) {
    const float* x = nullptr; const float* W = nullptr; const float* bias = nullptr;
    for (int i = 0; i < n_in; i++) {
        if      (in_sizes[i] == M_DIM * K_DIM) x    = (const float*)d_in[i];
        else if (in_sizes[i] == N_DIM * K_DIM) W    = (const float*)d_in[i];
        else if (in_sizes[i] == N_DIM)         bias = (const float*)d_in[i];
    }
    if (!x)    x    = (const float*)d_in[0];
    if (!W)    W    = (const float*)d_in[1];
    if (!bias) bias = (const float*)d_in[2];
    float* out = (float*)d_out;

    // workspace layout
    const size_t off_cnt = 0;
    const size_t off_wl  = 64;
    const size_t off_Ah  = off_wl + (size_t)NCHAIN * 4;          // 1048640
    const size_t szA     = (size_t)M_DIM * K_DIM * 2;            // 32 MiB
    const size_t szW     = (size_t)N_DIM * K_DIM * 2;            //  8 MiB
    const size_t off_Al  = off_Ah + szA;
    const size_t off_Wh  = off_Al + szA;
    const size_t off_Wl  = off_Wh + szW;
    const size_t need    = off_Wl + szW;                         // ~81 MiB

    if (ws_size < need) {
        // fallback: known-passing fused exact kernel (R8)
        dim3 grid(N_DIM / 64, BATCH);
        lif_openblas_q320<<<grid, 256, 0, stream>>>(x, W, bias, out);
        return;
    }

    char* ws = (char*)d_ws;
    unsigned int* counter  = (unsigned int*)(ws + off_cnt);
    unsigned int* worklist = (unsigned int*)(ws + off_wl);
    u16* Ah = (u16*)(ws + off_Ah);
    u16* Al = (u16*)(ws + off_Al);
    u16* Wh = (u16*)(ws + off_Wh);
    u16* Wl = (u16*)(ws + off_Wl);

    zero_u32<<<1, 1, 0, stream>>>(counter);
    split_bf16<<<(M_DIM * K_DIM / 4 + N_DIM * K_DIM / 4) / 256, 256, 0, stream>>>(
        x, W, Ah, Al, Wh, Wl);
    dim3 ggrid(N_DIM / 128, M_DIM / 128);   // (16, 64)
    gemm_bf16x3<<<ggrid, 256, 0, stream>>>(Ah, Al, Wh, Wl, bias, out);
    lif_scan_band<<<NCHAIN / 256, 256, 0, stream>>>(out, counter, worklist);
    lif_repair<<<4096, 64, 0, stream>>>(x, W, bias, counter, worklist, out);
}

// Round 10
// 549.496 us; speedup vs baseline: 2.8892x; 2.8892x over previous
//
#include <hip/hip_runtime.h>
#include <hip/hip_bf16.h>
#include <math.h>

// ---------------------------------------------------------------------------
// LIF layer, round 10: bf16x3 MFMA GEMM + banded scan + b-GROUPED exact repair.
//
// R9 lesson: fast+repair is CORRECT (absmax=0.0) but repair v1 (one block per
// flagged chain, random order) re-streamed the same per-b X slab ~43x ->
// 2.85 GB fetch, 1210 us. v2 groups flagged chains by batch row b and
// repairs 16 chains per block from one LDS-staged X chunk; BAND tightened
// 2e-3 -> 5e-4 (error tail ~6e-5 incl. scan amplification; 8x margin).
//
// Pipeline:
//   k1 zero    : 128 per-b worklist counters = 0
//   k2 split   : A,W f32 -> bf16 hi/lo (Dekker, exact residual)
//   k3 gemm    : 128x128x32 MFMA tiles, hh+hl+lh, cur_fast -> d_out
//   k4 scan    : exact-f32 scan, spikes in place, tight chains -> worklist[b]
//   k5 repair  : per (b, group of 16 chains): exact Q=320-panel dots from
//                LDS-staged X (64t x 64k chunks), exact scan, overwrite.
// Fallback (ws too small): R8 fused exact kernel (known-passing).
// ---------------------------------------------------------------------------

typedef unsigned short u16;
typedef __attribute__((ext_vector_type(8))) short bf16x8;
typedef __attribute__((ext_vector_type(4))) float f32x4;

constexpr int T_STEPS = 64;
constexpr int BATCH   = 128;
constexpr int K_DIM   = 2048;
constexpr int N_DIM   = 2048;
constexpr int M_DIM   = T_STEPS * BATCH;      // 8192
constexpr int NCHAIN  = BATCH * N_DIM;        // 262144

constexpr float DECAY_F32 = (float)0.6065306597126334;
constexpr float BAND      = 5e-4f;

// ---------------------------------------------------------------------------
__global__ void zero_counters(unsigned int* p) {
    if (threadIdx.x < 128) p[threadIdx.x] = 0u;
}

// ---------------------------------------------------------------------------
// k2: Dekker split f32 -> bf16 hi/lo, 4 elems/thread.
// ---------------------------------------------------------------------------
__global__ __launch_bounds__(256)
void split_bf16(const float* __restrict__ X, const float* __restrict__ W,
                u16* __restrict__ Ah, u16* __restrict__ Al,
                u16* __restrict__ Wh, u16* __restrict__ Wl) {
    constexpr int NA4 = (M_DIM * K_DIM) / 4;
    constexpr int NW4 = (N_DIM * K_DIM) / 4;
    const int i = blockIdx.x * 256 + threadIdx.x;
    const float* src; u16* dh; u16* dl; int base;
    if (i < NA4)            { src = X; dh = Ah; dl = Al; base = i; }
    else if (i < NA4 + NW4) { src = W; dh = Wh; dl = Wl; base = i - NA4; }
    else return;

    const float4 v = *(const float4*)(src + (size_t)base * 4);
    const float f[4] = {v.x, v.y, v.z, v.w};
    unsigned int hp[2], lp[2];
#pragma unroll
    for (int q = 0; q < 4; q += 2) {
        u16 hh[2], ll[2];
#pragma unroll
        for (int e = 0; e < 2; e++) {
            __hip_bfloat16 hb = __float2bfloat16(f[q + e]);
            const float hf = __bfloat162float(hb);
            __hip_bfloat16 lb = __float2bfloat16(f[q + e] - hf);
            hh[e] = *(u16*)&hb;
            ll[e] = *(u16*)&lb;
        }
        hp[q >> 1] = (unsigned int)hh[0] | ((unsigned int)hh[1] << 16);
        lp[q >> 1] = (unsigned int)ll[0] | ((unsigned int)ll[1] << 16);
    }
    *(uint2*)(dh + (size_t)base * 4) = make_uint2(hp[0], hp[1]);
    *(uint2*)(dl + (size_t)base * 4) = make_uint2(lp[0], lp[1]);
}

// ---------------------------------------------------------------------------
// k3: bf16x3 MFMA GEMM (hh + hl + lh). 128x128 tile, BK=32, 4 waves 2x2.
// ---------------------------------------------------------------------------
__global__ __launch_bounds__(256, 2)
void gemm_bf16x3(const u16* __restrict__ Ah, const u16* __restrict__ Al,
                 const u16* __restrict__ Bh, const u16* __restrict__ Bl,
                 const float* __restrict__ bias, float* __restrict__ C) {
    __shared__ __align__(16) u16 sAh[4096], sAl[4096], sBh[4096], sBl[4096];

    const int tid  = threadIdx.x;
    const int m0   = blockIdx.y * 128;
    const int n0   = blockIdx.x * 128;
    const int lane = tid & 63;
    const int wave = tid >> 6;
    const int wm   = wave >> 1;
    const int wn   = wave & 1;

    const int c0 = tid, c1 = tid + 256;
#define OFFA(c) ((size_t)(m0 + ((c) >> 6) * 16 + ((c) & 15)) * K_DIM + (((c) >> 4) & 3) * 8)
#define OFFB(c) ((size_t)(n0 + ((c) >> 6) * 16 + ((c) & 15)) * K_DIM + (((c) >> 4) & 3) * 8)
    const size_t a0 = OFFA(c0), a1 = OFFA(c1);
    const size_t b0 = OFFB(c0), b1 = OFFB(c1);
#undef OFFA
#undef OFFB

    f32x4 acc[4][4];
#pragma unroll
    for (int i = 0; i < 4; i++)
#pragma unroll
        for (int j = 0; j < 4; j++) acc[i][j] = (f32x4){0.f, 0.f, 0.f, 0.f};

    for (int kc = 0; kc < K_DIM / 32; kc++) {
        const int k0 = kc * 32;
        const uint4 vah0 = *(const uint4*)(Ah + a0 + k0);
        const uint4 vah1 = *(const uint4*)(Ah + a1 + k0);
        const uint4 val0 = *(const uint4*)(Al + a0 + k0);
        const uint4 val1 = *(const uint4*)(Al + a1 + k0);
        const uint4 vbh0 = *(const uint4*)(Bh + b0 + k0);
        const uint4 vbh1 = *(const uint4*)(Bh + b1 + k0);
        const uint4 vbl0 = *(const uint4*)(Bl + b0 + k0);
        const uint4 vbl1 = *(const uint4*)(Bl + b1 + k0);
        __syncthreads();
        *(uint4*)&sAh[c0 * 8] = vah0;  *(uint4*)&sAh[c1 * 8] = vah1;
        *(uint4*)&sAl[c0 * 8] = val0;  *(uint4*)&sAl[c1 * 8] = val1;
        *(uint4*)&sBh[c0 * 8] = vbh0;  *(uint4*)&sBh[c1 * 8] = vbh1;
        *(uint4*)&sBl[c0 * 8] = vbl0;  *(uint4*)&sBl[c1 * 8] = vbl1;
        __syncthreads();

        bf16x8 fah[4], fal[4], fbh[4], fbl[4];
#pragma unroll
        for (int ti = 0; ti < 4; ti++) {
            const int ta = wm * 4 + ti;
            fah[ti] = *(const bf16x8*)&sAh[(ta * 64 + lane) * 8];
            fal[ti] = *(const bf16x8*)&sAl[(ta * 64 + lane) * 8];
        }
#pragma unroll
        for (int tj = 0; tj < 4; tj++) {
            const int tb = wn * 4 + tj;
            fbh[tj] = *(const bf16x8*)&sBh[(tb * 64 + lane) * 8];
            fbl[tj] = *(const bf16x8*)&sBl[(tb * 64 + lane) * 8];
        }
#pragma unroll
        for (int ti = 0; ti < 4; ti++)
#pragma unroll
            for (int tj = 0; tj < 4; tj++) {
                acc[ti][tj] = __builtin_amdgcn_mfma_f32_16x16x32_bf16(
                    fah[ti], fbh[tj], acc[ti][tj], 0, 0, 0);
                acc[ti][tj] = __builtin_amdgcn_mfma_f32_16x16x32_bf16(
                    fah[ti], fbl[tj], acc[ti][tj], 0, 0, 0);
                acc[ti][tj] = __builtin_amdgcn_mfma_f32_16x16x32_bf16(
                    fal[ti], fbh[tj], acc[ti][tj], 0, 0, 0);
            }
    }

#pragma unroll
    for (int tj = 0; tj < 4; tj++) {
        const int n  = n0 + wn * 64 + tj * 16 + (lane & 15);
        const float bv = bias[n];
#pragma unroll
        for (int ti = 0; ti < 4; ti++) {
            const int mbase = m0 + wm * 64 + ti * 16 + (lane >> 4) * 4;
#pragma unroll
            for (int r = 0; r < 4; r++)
                C[(size_t)(mbase + r) * N_DIM + n] = acc[ti][tj][r] + bv;
        }
    }
}

// ---------------------------------------------------------------------------
// k4: banded scan; flagged chains go to per-b worklists.
// ---------------------------------------------------------------------------
__global__ __launch_bounds__(256)
void lif_scan_band(float* __restrict__ buf, unsigned int* __restrict__ counters,
                   unsigned int* __restrict__ worklist) {
    const int idx = blockIdx.x * 256 + threadIdx.x;   // chain = b*2048 + o
    float mem = 0.0f;
    bool flag = false;
#pragma unroll
    for (int t = 0; t < T_STEPS; t++) {
        const size_t off = (size_t)t * NCHAIN + idx;
        mem = __fadd_rn(__fmul_rn(mem, DECAY_F32), buf[off]);
        const float d = __fsub_rn(mem, 1.0f);
        const bool spk = d > 0.0f;
        if (fabsf(d) < BAND) flag = true;
        buf[off] = spk ? 1.0f : 0.0f;
        if (spk) mem = __fsub_rn(mem, 1.0f);
    }
    if (flag) {
        const int b = idx >> 11, o = idx & 2047;
        const unsigned int p = atomicAdd(&counters[b], 1u);
        worklist[b * 2048 + p] = (unsigned int)o;
    }
}

// ---------------------------------------------------------------------------
// k5: b-grouped exact repair. Block = (b, group-stride j). 256 thr = 64t x 4oi;
// each thread computes 4 exact Q=320-panel dots from LDS-staged X/W chunks.
// ---------------------------------------------------------------------------
#define RG 16    // chains per group
#define RJ 4     // block-strides per b
#define BKR 64   // k-chunk (320 = 5*64: panel boundaries land on chunk edges)

__global__ __launch_bounds__(256)
void lif_repair2(const float* __restrict__ X, const float* __restrict__ W,
                 const float* __restrict__ bias,
                 const unsigned int* __restrict__ counters,
                 const unsigned int* __restrict__ worklist,
                 float* __restrict__ out) {
    __shared__ float sX[BKR][T_STEPS + 1];      // [k][t] 16.25 KiB
    __shared__ float sW[RG][BKR + 1];           // [o][k]  4.06 KiB
    __shared__ float scur[T_STEPS][RG + 1];
    __shared__ float sspk[T_STEPS][RG + 1];
    __shared__ int   so[RG];

    const int b = blockIdx.x / RJ;
    const int j = blockIdx.x % RJ;
    const unsigned int n_b = counters[b];
    if (n_b == 0) return;
    const int ngroups = (int)(n_b + RG - 1) / RG;

    const int tid = threadIdx.x;
    const int t   = tid & 63;
    const int oi  = tid >> 6;          // 0..3, owns o-slots 4*oi .. 4*oi+3

    for (int g = j; g < ngroups; g += RJ) {
        if (tid < RG) {
            const int slot = g * RG + tid;
            so[tid] = (slot < (int)n_b) ? (int)worklist[b * 2048 + slot] : -1;
        }
        __syncthreads();

        float Csum[4] = {0.f, 0.f, 0.f, 0.f};
        float P[4]    = {0.f, 0.f, 0.f, 0.f};

        for (int c = 0; c < K_DIM / BKR; c++) {
            if (c > 0 && (c % 5) == 0) {       // k = 320*j panel boundary
#pragma unroll
                for (int q = 0; q < 4; q++) {
                    Csum[q] = __fadd_rn(Csum[q], P[q]);
                    P[q] = 0.f;
                }
            }
            const int k0 = c * BKR;
            // stage X chunk: 64 t x 64 k, 4 float4 per thread
            {
                const int ts = tid & 63;
                const int kq = (tid >> 6) * 16;
                const float* src = &X[(size_t)(ts * BATCH + b) * K_DIM + k0 + kq];
#pragma unroll
                for (int q = 0; q < 4; q++) {
                    const float4 v = *(const float4*)(src + q * 4);
                    sX[kq + q * 4 + 0][ts] = v.x;
                    sX[kq + q * 4 + 1][ts] = v.y;
                    sX[kq + q * 4 + 2][ts] = v.z;
                    sX[kq + q * 4 + 3][ts] = v.w;
                }
            }
            // stage W chunk: 16 o x 64 k, 1 float4 per thread
            {
                const int wo  = tid >> 4;          // 0..15
                const int wkq = (tid & 15) * 4;    // 0..60
                const int o   = so[wo];
                float4 v = {0.f, 0.f, 0.f, 0.f};
                if (o >= 0) v = *(const float4*)&W[(size_t)o * K_DIM + k0 + wkq];
                sW[wo][wkq + 0] = v.x; sW[wo][wkq + 1] = v.y;
                sW[wo][wkq + 2] = v.z; sW[wo][wkq + 3] = v.w;
            }
            __syncthreads();
            // exact sequential-k FMA, 4 independent chains (ILP)
#pragma unroll 8
            for (int k = 0; k < BKR; k++) {
                const float xv = sX[k][t];
#pragma unroll
                for (int q = 0; q < 4; q++)
                    P[q] = fmaf(xv, sW[oi * 4 + q][k], P[q]);
            }
            __syncthreads();
        }
#pragma unroll
        for (int q = 0; q < 4; q++) {
            Csum[q] = __fadd_rn(Csum[q], P[q]);    // final 128-elem panel
            const int o = so[oi * 4 + q];
            scur[t][oi * 4 + q] = (o >= 0) ? __fadd_rn(Csum[q], bias[o]) : 0.f;
        }
        __syncthreads();
        if (tid < RG && so[tid] >= 0) {
            float mem = 0.0f;
            for (int tt = 0; tt < T_STEPS; tt++) {
                mem = __fadd_rn(__fmul_rn(mem, DECAY_F32), scur[tt][tid]);
                const float d = __fsub_rn(mem, 1.0f);
                const bool spk = d > 0.0f;
                sspk[tt][tid] = spk ? 1.0f : 0.0f;
                if (spk) mem = __fsub_rn(mem, 1.0f);
            }
        }
        __syncthreads();
#pragma unroll
        for (int q = 0; q < 4; q++) {
            const int o = so[oi * 4 + q];
            if (o >= 0)
                out[(size_t)t * NCHAIN + (size_t)b * N_DIM + o] = sspk[t][oi * 4 + q];
        }
        __syncthreads();
    }
}

// ---------------------------------------------------------------------------
// FALLBACK (R8, known-passing, ws-free).
// ---------------------------------------------------------------------------
__global__ __launch_bounds__(256)
void lif_openblas_q320(const float* __restrict__ X, const float* __restrict__ W,
                       const float* __restrict__ bias, float* __restrict__ out) {
    __shared__ float As[16][T_STEPS + 4];
    __shared__ float Ws[16][64 + 4];
    __shared__ float curbuf[T_STEPS][64 + 1];
    const int tid = threadIdx.x;
    const int o0 = blockIdx.x * 64, b0 = blockIdx.y;
    const int tm = (tid & 15) * 4, tn = (tid >> 4) * 4;
    float Csum[4][4], Pacc[4][4];
#pragma unroll
    for (int i = 0; i < 4; i++)
#pragma unroll
        for (int j = 0; j < 4; j++) { Csum[i][j] = 0.f; Pacc[i][j] = 0.f; }
    for (int c = 0; c < K_DIM / 16; c++) {
        if (c > 0 && (c % 20) == 0) {
#pragma unroll
            for (int i = 0; i < 4; i++)
#pragma unroll
                for (int j = 0; j < 4; j++) {
                    Csum[i][j] = __fadd_rn(Csum[i][j], Pacc[i][j]);
                    Pacc[i][j] = 0.f;
                }
        }
        const int k0 = c * 16;
        {
            const int t = tid >> 2, kq = (tid & 3) * 4;
            const float4 av = *(const float4*)&X[(size_t)(t * BATCH + b0) * K_DIM + k0 + kq];
            As[kq + 0][t] = av.x; As[kq + 1][t] = av.y;
            As[kq + 2][t] = av.z; As[kq + 3][t] = av.w;
            const float4 wv = *(const float4*)&W[(size_t)(o0 + t) * K_DIM + k0 + kq];
            Ws[kq + 0][t] = wv.x; Ws[kq + 1][t] = wv.y;
            Ws[kq + 2][t] = wv.z; Ws[kq + 3][t] = wv.w;
        }
        __syncthreads();
#pragma unroll
        for (int k = 0; k < 16; k++) {
            float a[4], w[4];
#pragma unroll
            for (int i = 0; i < 4; i++) a[i] = As[k][tm + i];
#pragma unroll
            for (int j = 0; j < 4; j++) w[j] = Ws[k][tn + j];
#pragma unroll
            for (int i = 0; i < 4; i++)
#pragma unroll
                for (int j = 0; j < 4; j++) Pacc[i][j] = fmaf(a[i], w[j], Pacc[i][j]);
        }
        __syncthreads();
    }
#pragma unroll
    for (int i = 0; i < 4; i++)
#pragma unroll
        for (int j = 0; j < 4; j++)
            curbuf[tm + i][tn + j] =
                __fadd_rn(__fadd_rn(Csum[i][j], Pacc[i][j]), bias[o0 + tn + j]);
    __syncthreads();
    if (tid < 64) {
        float mem = 0.0f;
#pragma unroll
        for (int t = 0; t < T_STEPS; t++) {
            mem = __fadd_rn(__fmul_rn(mem, DECAY_F32), curbuf[t][tid]);
            const float d = __fsub_rn(mem, 1.0f);
            const bool spk = d > 0.0f;
            out[(size_t)t * NCHAIN + (size_t)b0 * N_DIM + o0 + tid] = spk ? 1.0f : 0.0f;
            if (spk) mem = __fsub_rn(mem, 1.0f);
        }
    }
}

extern "C" void kernel_launch(void* const* d_in, const int* in_sizes, int n_in,
                              void* d_out, int out_size, void* d_ws, size_t ws_size,
                              hipStream_t stream) {
    const float* x = nullptr; const float* W = nullptr; const float* bias = nullptr;
    for (int i = 0; i < n_in; i++) {
        if      (in_sizes[i] == M_DIM * K_DIM) x    = (const float*)d_in[i];
        else if (in_sizes[i] == N_DIM * K_DIM) W    = (const float*)d_in[i];
        else if (in_sizes[i] == N_DIM)         bias = (const float*)d_in[i];
    }
    if (!x)    x    = (const float*)d_in[0];
    if (!W)    W    = (const float*)d_in[1];
    if (!bias) bias = (const float*)d_in[2];
    float* out = (float*)d_out;

    // workspace layout
    const size_t off_cnt = 0;                                     // 128 u32
    const size_t off_wl  = 512;                                   // 128*2048 u32
    const size_t off_Ah  = off_wl + (size_t)128 * 2048 * 4;       // 1049088
    const size_t szA     = (size_t)M_DIM * K_DIM * 2;             // 32 MiB
    const size_t szW     = (size_t)N_DIM * K_DIM * 2;             //  8 MiB
    const size_t off_Al  = off_Ah + szA;
    const size_t off_Wh  = off_Al + szA;
    const size_t off_Wl  = off_Wh + szW;
    const size_t need    = off_Wl + szW;

    if (ws_size < need) {
        dim3 grid(N_DIM / 64, BATCH);
        lif_openblas_q320<<<grid, 256, 0, stream>>>(x, W, bias, out);
        return;
    }

    char* ws = (char*)d_ws;
    unsigned int* counters = (unsigned int*)(ws + off_cnt);
    unsigned int* worklist = (unsigned int*)(ws + off_wl);
    u16* Ah = (u16*)(ws + off_Ah);
    u16* Al = (u16*)(ws + off_Al);
    u16* Wh = (u16*)(ws + off_Wh);
    u16* Wl = (u16*)(ws + off_Wl);

    zero_counters<<<1, 128, 0, stream>>>(counters);
    split_bf16<<<(M_DIM * K_DIM / 4 + N_DIM * K_DIM / 4) / 256, 256, 0, stream>>>(
        x, W, Ah, Al, Wh, Wl);
    dim3 ggrid(N_DIM / 128, M_DIM / 128);   // (16, 64)
    gemm_bf16x3<<<ggrid, 256, 0, stream>>>(Ah, Al, Wh, Wl, bias, out);
    lif_scan_band<<<NCHAIN / 256, 256, 0, stream>>>(out, counters, worklist);
    lif_repair2<<<128 * RJ, 256, 0, stream>>>(x, W, bias, counters, worklist, out);
}